// Round 1
// baseline (90.151 us; speedup 1.0000x reference)
//
#include <hip/hip_runtime.h>
#include <hip/hip_bf16.h>
#include <stdint.h>

#define B_DIM 8
#define L_DIM 64
#define F_DIM 64
#define R_DIM 2048
#define M_DIM 512      // B*F
#define K_DIM 4096     // 2*R (concat arg1|arg2 along K)
#define N_DIM 2048     // s

typedef _Float16 half_t;
typedef _Float16 half4 __attribute__((ext_vector_type(4)));
typedef _Float16 half8 __attribute__((ext_vector_type(8)));
typedef float floatx4 __attribute__((ext_vector_type(4)));

// ---------------- kernel 1: weighted reduce over L ----------------
// x:[B,L,F,R] f32, w1/w2:[B,L].  Writes A (fp16) [512][4096]:
//   A[b*64+f][r]       = sum_l x[b,l,f,r]*w1[b,l]
//   A[b*64+f][2048+r]  = sum_l x[b,l,f,r]*w2[b,l]
__global__ __launch_bounds__(256) void k_reduce(
    const float* __restrict__ x, const float* __restrict__ w1,
    const float* __restrict__ w2, half_t* __restrict__ Ah)
{
    __shared__ float w1s[L_DIM], w2s[L_DIM];
    const int tid = threadIdx.x;
    const int bid = blockIdx.x;            // 0..1023
    const int bf  = bid >> 1;              // output row m = b*64+f
    const int b   = bf >> 6;
    const int f   = bf & 63;
    if (tid < L_DIM) {
        w1s[tid] = w1[b * L_DIM + tid];
        w2s[tid] = w2[b * L_DIM + tid];
    }
    __syncthreads();
    const int r0 = (bid & 1) * 1024 + tid * 4;
    const float4* xp = (const float4*)(x + ((size_t)(b * 4096 + f)) * 2048 + r0);
    float a1x=0.f,a1y=0.f,a1z=0.f,a1w=0.f;
    float a2x=0.f,a2y=0.f,a2z=0.f,a2w=0.f;
    #pragma unroll 8
    for (int l = 0; l < L_DIM; ++l) {
        float4 v = xp[(size_t)l * (F_DIM * R_DIM / 4)];   // stride F*R floats
        float u1 = w1s[l], u2 = w2s[l];
        a1x += v.x*u1; a1y += v.y*u1; a1z += v.z*u1; a1w += v.w*u1;
        a2x += v.x*u2; a2y += v.y*u2; a2z += v.z*u2; a2w += v.w*u2;
    }
    half4 h1 = { (half_t)a1x, (half_t)a1y, (half_t)a1z, (half_t)a1w };
    half4 h2 = { (half_t)a2x, (half_t)a2y, (half_t)a2z, (half_t)a2w };
    *(half4*)(Ah + (size_t)bf * K_DIM + r0) = h1;
    *(half4*)(Ah + (size_t)bf * K_DIM + R_DIM + r0) = h2;
}

// ---------------- kernel 2: cons_l/cons_r -> fp16 B^T layout ----------------
// B[s][k]: k<2048 -> cons_l[s][k], k>=2048 -> cons_r[s][k-2048]
__global__ __launch_bounds__(256) void k_conv(
    const float* __restrict__ cl, const float* __restrict__ cr,
    half_t* __restrict__ Bh)
{
    const int i = (blockIdx.x * 256 + threadIdx.x) * 4;   // 0 .. 4M-4
    const int s = i >> 11;
    const int r = i & 2047;
    float4 vl = *(const float4*)(cl + i);
    float4 vr = *(const float4*)(cr + i);
    half4 hl = { (half_t)vl.x, (half_t)vl.y, (half_t)vl.z, (half_t)vl.w };
    half4 hr = { (half_t)vr.x, (half_t)vr.y, (half_t)vr.z, (half_t)vr.w };
    *(half4*)(Bh + (size_t)s * K_DIM + r) = hl;
    *(half4*)(Bh + (size_t)s * K_DIM + R_DIM + r) = hr;
}

// ---------------- kernel 3: row maxes ----------------
__global__ __launch_bounds__(512) void k_max(
    const float* __restrict__ w1, const float* __restrict__ w2,
    float* __restrict__ out)
{
    const int tid = threadIdx.x;
    const int b = tid >> 6, l = tid & 63;
    float v1 = w1[b * 64 + l];
    float v2 = w2[b * 64 + l];
    #pragma unroll
    for (int off = 32; off > 0; off >>= 1) {
        v1 = fmaxf(v1, __shfl_down(v1, off));
        v2 = fmaxf(v2, __shfl_down(v2, off));
    }
    if (l == 0) {
        out[M_DIM * N_DIM + b]     = v1;
        out[M_DIM * N_DIM + 8 + b] = v2;
    }
}

// ---------------- kernel 4: MFMA GEMM with split-K ----------------
__device__ __forceinline__ void gload16(void* lds, const void* g)
{
    __builtin_amdgcn_global_load_lds(
        (const __attribute__((address_space(1))) void*)g,
        (__attribute__((address_space(3))) void*)lds, 16, 0, 0);
}

#define BM 128
#define BN 128
#define BK 64
#define SPLITK 8
#define KSEG (K_DIM / SPLITK)  // 512
#define NSTEP (KSEG / BK)      // 8

__global__ __launch_bounds__(256) void k_gemm(
    const half_t* __restrict__ Ah, const half_t* __restrict__ Bh,
    float* __restrict__ part)
{
    // LDS tiles [128 rows][64 halfs], XOR-swizzled: logical col-block cb of
    // row lives at physical slot cb ^ (row&7). global_load_lds writes
    // linearly (base + lane*16B), so the swizzle is applied by permuting the
    // per-lane GLOBAL source address (m173 pattern).
    __shared__ half_t sA[2][BM * BK];
    __shared__ half_t sB[2][BN * BK];
    const int tid  = threadIdx.x;
    const int lane = tid & 63;
    const int w    = tid >> 6;           // wave 0..3
    const int wr   = w >> 1, wc = w & 1; // 2x2 wave grid, 64x64 each
    const int m0   = blockIdx.y * BM;
    const int n0   = blockIdx.x * BN;
    const int kz   = blockIdx.z * KSEG;

    const int srow = lane >> 3;                    // dest row within 8-row chunk
    const int scol = ((lane & 7) ^ srow) << 3;     // swizzled source col (halfs)

    const floatx4 fzero = { 0.f, 0.f, 0.f, 0.f };
    floatx4 acc[4][4];
    #pragma unroll
    for (int i = 0; i < 4; ++i)
        #pragma unroll
        for (int j = 0; j < 4; ++j) acc[i][j] = fzero;

    auto stage = [&](int buf, int kt) {
        #pragma unroll
        for (int c = 0; c < 4; ++c) {
            const int rbase = w * 32 + c * 8;      // wave-uniform
            const int row   = rbase + srow;
            gload16(&sA[buf][rbase * BK], Ah + (size_t)(m0 + row) * K_DIM + kt + scol);
            gload16(&sB[buf][rbase * BK], Bh + (size_t)(n0 + row) * K_DIM + kt + scol);
        }
    };

    stage(0, kz);
    __syncthreads();

    const int l15 = lane & 15, l4 = lane >> 4;
    int buf = 0;
    for (int ks = 0; ks < NSTEP; ++ks) {
        if (ks + 1 < NSTEP) stage(buf ^ 1, kz + (ks + 1) * BK);
        #pragma unroll
        for (int ksub = 0; ksub < 2; ++ksub) {
            half8 af[4], bfr[4];
            const int cb = ksub * 4 + l4;          // logical col-block 0..7
            #pragma unroll
            for (int mi = 0; mi < 4; ++mi) {
                const int row = wr * 64 + mi * 16 + l15;
                af[mi] = *(const half8*)&sA[buf][row * BK + ((cb ^ (row & 7)) << 3)];
            }
            #pragma unroll
            for (int ni = 0; ni < 4; ++ni) {
                const int row = wc * 64 + ni * 16 + l15;
                bfr[ni] = *(const half8*)&sB[buf][row * BK + ((cb ^ (row & 7)) << 3)];
            }
            #pragma unroll
            for (int mi = 0; mi < 4; ++mi)
                #pragma unroll
                for (int ni = 0; ni < 4; ++ni)
                    acc[mi][ni] = __builtin_amdgcn_mfma_f32_16x16x32_f16(
                        af[mi], bfr[ni], acc[mi][ni], 0, 0, 0);
        }
        __syncthreads();
        buf ^= 1;
    }

    float* P = part + (size_t)blockIdx.z * ((size_t)M_DIM * N_DIM);
    #pragma unroll
    for (int mi = 0; mi < 4; ++mi) {
        const int rb = m0 + wr * 64 + mi * 16 + l4 * 4;
        #pragma unroll
        for (int ni = 0; ni < 4; ++ni) {
            const int cc = n0 + wc * 64 + ni * 16 + l15;
            #pragma unroll
            for (int r = 0; r < 4; ++r)
                P[(size_t)(rb + r) * N_DIM + cc] = acc[mi][ni][r];
        }
    }
}

// ---------------- kernel 5: reduce split-K partials + root outer product ----------------
__global__ __launch_bounds__(256) void k_final(
    const float* __restrict__ part, const float* __restrict__ filler,
    const float* __restrict__ role, float* __restrict__ out)
{
    const int idx = (blockIdx.x * 256 + threadIdx.x) * 4;  // over 1M outputs
    const int mfi = idx >> 11;          // b*64+f
    const int s   = idx & 2047;
    float4 a = *(const float4*)(part + idx);
    #pragma unroll
    for (int z = 1; z < SPLITK; ++z) {
        float4 p = *(const float4*)(part + (size_t)z * (M_DIM * N_DIM) + idx);
        a.x += p.x; a.y += p.y; a.z += p.z; a.w += p.w;
    }
    const float fl = filler[mfi];
    float4 ro = *(const float4*)(role + s);
    a.x += fl * ro.x; a.y += fl * ro.y; a.z += fl * ro.z; a.w += fl * ro.w;
    *(float4*)(out + idx) = a;
}

extern "C" void kernel_launch(void* const* d_in, const int* in_sizes, int n_in,
                              void* d_out, int out_size, void* d_ws, size_t ws_size,
                              hipStream_t stream)
{
    const float* x      = (const float*)d_in[0];
    const float* w1     = (const float*)d_in[1];
    const float* w2     = (const float*)d_in[2];
    const float* filler = (const float*)d_in[3];
    const float* cl     = (const float*)d_in[4];
    const float* cr     = (const float*)d_in[5];
    const float* role   = (const float*)d_in[6];
    float* out = (float*)d_out;

    char* ws = (char*)d_ws;
    half_t* Ah  = (half_t*)ws;                       // 512*4096*2   = 4 MiB
    half_t* Bh  = (half_t*)(ws + (4u << 20));        // 2048*4096*2  = 16 MiB
    float*  prt = (float*)(ws + (20u << 20));        // 8*512*2048*4 = 32 MiB

    hipLaunchKernelGGL(k_reduce, dim3(1024), dim3(256), 0, stream, x, w1, w2, Ah);
    hipLaunchKernelGGL(k_conv,   dim3(4096), dim3(256), 0, stream, cl, cr, Bh);
    hipLaunchKernelGGL(k_max,    dim3(1),    dim3(512), 0, stream, w1, w2, out);
    hipLaunchKernelGGL(k_gemm,   dim3(N_DIM / BN, M_DIM / BM, SPLITK), dim3(256), 0, stream,
                       Ah, Bh, prt);
    hipLaunchKernelGGL(k_final,  dim3(1024), dim3(256), 0, stream, prt, filler, role, out);
}

// Round 2
// 87.065 us; speedup vs baseline: 1.0354x; 1.0354x over previous
//
#include <hip/hip_runtime.h>
#include <hip/hip_bf16.h>
#include <stdint.h>

#define B_DIM 8
#define L_DIM 64
#define F_DIM 64
#define R_DIM 2048
#define M_DIM 512      // B*F
#define K_DIM 4096     // 2*R (concat arg1|arg2 along K)
#define N_DIM 2048     // s

typedef _Float16 half_t;
typedef _Float16 half4 __attribute__((ext_vector_type(4)));
typedef _Float16 half8 __attribute__((ext_vector_type(8)));
typedef float floatx4 __attribute__((ext_vector_type(4)));

// ---------------- kernel 1 (fused front): ----------------
// blocks 0..1023     : weighted reduce over L  -> Ah [512][4096] fp16
// blocks 1024..5119  : cons_l/cons_r f32 -> fp16 B^T layout [2048][4096]
// block  5120        : row maxes of w1/w2 -> out[1M .. 1M+15]
__global__ __launch_bounds__(256) void k_front(
    const float* __restrict__ x, const float* __restrict__ w1,
    const float* __restrict__ w2, const float* __restrict__ cl,
    const float* __restrict__ cr, half_t* __restrict__ Ah,
    half_t* __restrict__ Bh, float* __restrict__ out)
{
    const int tid = threadIdx.x;
    const int bid = blockIdx.x;

    if (bid < 1024) {
        // ---- weighted reduce over L ----
        __shared__ float w1s[L_DIM], w2s[L_DIM];
        const int bf  = bid >> 1;              // output row m = b*64+f
        const int b   = bf >> 6;
        const int f   = bf & 63;
        if (tid < L_DIM) {
            w1s[tid] = w1[b * L_DIM + tid];
            w2s[tid] = w2[b * L_DIM + tid];
        }
        __syncthreads();
        const int r0 = (bid & 1) * 1024 + tid * 4;
        const float4* xp = (const float4*)(x + ((size_t)(b * 4096 + f)) * 2048 + r0);
        float a1x=0.f,a1y=0.f,a1z=0.f,a1w=0.f;
        float a2x=0.f,a2y=0.f,a2z=0.f,a2w=0.f;
        #pragma unroll 8
        for (int l = 0; l < L_DIM; ++l) {
            float4 v = xp[(size_t)l * (F_DIM * R_DIM / 4)];   // stride F*R floats
            float u1 = w1s[l], u2 = w2s[l];
            a1x += v.x*u1; a1y += v.y*u1; a1z += v.z*u1; a1w += v.w*u1;
            a2x += v.x*u2; a2y += v.y*u2; a2z += v.z*u2; a2w += v.w*u2;
        }
        half4 h1 = { (half_t)a1x, (half_t)a1y, (half_t)a1z, (half_t)a1w };
        half4 h2 = { (half_t)a2x, (half_t)a2y, (half_t)a2z, (half_t)a2w };
        *(half4*)(Ah + (size_t)bf * K_DIM + r0) = h1;
        *(half4*)(Ah + (size_t)bf * K_DIM + R_DIM + r0) = h2;
    } else if (bid < 5120) {
        // ---- cons conversion to fp16 B^T layout ----
        const int i = ((bid - 1024) * 256 + tid) * 4;   // 0 .. 4M-4
        const int s = i >> 11;
        const int r = i & 2047;
        float4 vl = *(const float4*)(cl + i);
        float4 vr = *(const float4*)(cr + i);
        half4 hl = { (half_t)vl.x, (half_t)vl.y, (half_t)vl.z, (half_t)vl.w };
        half4 hr = { (half_t)vr.x, (half_t)vr.y, (half_t)vr.z, (half_t)vr.w };
        *(half4*)(Bh + (size_t)s * K_DIM + r) = hl;
        *(half4*)(Bh + (size_t)s * K_DIM + R_DIM + r) = hr;
    } else {
        // ---- row maxes ----
        if (tid < 16) {
            const float* src = (tid < 8) ? w1 : w2;
            const int b = tid & 7;
            float m = -1.f;
            #pragma unroll 8
            for (int l = 0; l < L_DIM; ++l)
                m = fmaxf(m, src[b * L_DIM + l]);
            out[M_DIM * N_DIM + tid] = m;
        }
    }
}

// ---------------- kernel 2: MFMA GEMM with split-K ----------------
__device__ __forceinline__ void gload16(void* lds, const void* g)
{
    __builtin_amdgcn_global_load_lds(
        (const __attribute__((address_space(1))) void*)g,
        (__attribute__((address_space(3))) void*)lds, 16, 0, 0);
}

#define BM 128
#define BN 128
#define BK 64
#define SPLITK 8
#define KSEG (K_DIM / SPLITK)  // 512
#define NSTEP (KSEG / BK)      // 8

__global__ __launch_bounds__(256) void k_gemm(
    const half_t* __restrict__ Ah, const half_t* __restrict__ Bh,
    float* __restrict__ part)
{
    // LDS tiles [128 rows][64 halfs], XOR-swizzled: logical col-block cb of
    // row lives at physical slot cb ^ (row&7). global_load_lds writes
    // linearly (base + lane*16B), so the swizzle is applied by permuting the
    // per-lane GLOBAL source address (m173 pattern).
    __shared__ half_t sA[2][BM * BK];
    __shared__ half_t sB[2][BN * BK];
    const int tid  = threadIdx.x;
    const int lane = tid & 63;
    const int w    = tid >> 6;           // wave 0..3
    const int wr   = w >> 1, wc = w & 1; // 2x2 wave grid, 64x64 each
    const int m0   = blockIdx.y * BM;
    const int n0   = blockIdx.x * BN;
    const int kz   = blockIdx.z * KSEG;

    const int srow = lane >> 3;                    // dest row within 8-row chunk
    const int scol = ((lane & 7) ^ srow) << 3;     // swizzled source col (halfs)

    const floatx4 fzero = { 0.f, 0.f, 0.f, 0.f };
    floatx4 acc[4][4];
    #pragma unroll
    for (int i = 0; i < 4; ++i)
        #pragma unroll
        for (int j = 0; j < 4; ++j) acc[i][j] = fzero;

    auto stage = [&](int buf, int kt) {
        #pragma unroll
        for (int c = 0; c < 4; ++c) {
            const int rbase = w * 32 + c * 8;      // wave-uniform
            const int row   = rbase + srow;
            gload16(&sA[buf][rbase * BK], Ah + (size_t)(m0 + row) * K_DIM + kt + scol);
            gload16(&sB[buf][rbase * BK], Bh + (size_t)(n0 + row) * K_DIM + kt + scol);
        }
    };

    stage(0, kz);
    __syncthreads();

    const int l15 = lane & 15, l4 = lane >> 4;
    int buf = 0;
    for (int ks = 0; ks < NSTEP; ++ks) {
        if (ks + 1 < NSTEP) stage(buf ^ 1, kz + (ks + 1) * BK);
        #pragma unroll
        for (int ksub = 0; ksub < 2; ++ksub) {
            half8 af[4], bfr[4];
            const int cb = ksub * 4 + l4;          // logical col-block 0..7
            #pragma unroll
            for (int mi = 0; mi < 4; ++mi) {
                const int row = wr * 64 + mi * 16 + l15;
                af[mi] = *(const half8*)&sA[buf][row * BK + ((cb ^ (row & 7)) << 3)];
            }
            #pragma unroll
            for (int ni = 0; ni < 4; ++ni) {
                const int row = wc * 64 + ni * 16 + l15;
                bfr[ni] = *(const half8*)&sB[buf][row * BK + ((cb ^ (row & 7)) << 3)];
            }
            #pragma unroll
            for (int mi = 0; mi < 4; ++mi)
                #pragma unroll
                for (int ni = 0; ni < 4; ++ni)
                    acc[mi][ni] = __builtin_amdgcn_mfma_f32_16x16x32_f16(
                        af[mi], bfr[ni], acc[mi][ni], 0, 0, 0);
        }
        __syncthreads();
        buf ^= 1;
    }

    float* P = part + (size_t)blockIdx.z * ((size_t)M_DIM * N_DIM);
    #pragma unroll
    for (int mi = 0; mi < 4; ++mi) {
        const int rb = m0 + wr * 64 + mi * 16 + l4 * 4;
        #pragma unroll
        for (int ni = 0; ni < 4; ++ni) {
            const int cc = n0 + wc * 64 + ni * 16 + l15;
            #pragma unroll
            for (int r = 0; r < 4; ++r)
                P[(size_t)(rb + r) * N_DIM + cc] = acc[mi][ni][r];
        }
    }
}

// ---------------- kernel 3: reduce split-K partials + root outer product ----------------
__global__ __launch_bounds__(256) void k_final(
    const float* __restrict__ part, const float* __restrict__ filler,
    const float* __restrict__ role, float* __restrict__ out)
{
    const int idx = (blockIdx.x * 256 + threadIdx.x) * 4;  // over 1M outputs
    const int mfi = idx >> 11;          // b*64+f
    const int s   = idx & 2047;
    float4 a = *(const float4*)(part + idx);
    #pragma unroll
    for (int z = 1; z < SPLITK; ++z) {
        float4 p = *(const float4*)(part + (size_t)z * (M_DIM * N_DIM) + idx);
        a.x += p.x; a.y += p.y; a.z += p.z; a.w += p.w;
    }
    const float fl = filler[mfi];
    float4 ro = *(const float4*)(role + s);
    a.x += fl * ro.x; a.y += fl * ro.y; a.z += fl * ro.z; a.w += fl * ro.w;
    *(float4*)(out + idx) = a;
}

extern "C" void kernel_launch(void* const* d_in, const int* in_sizes, int n_in,
                              void* d_out, int out_size, void* d_ws, size_t ws_size,
                              hipStream_t stream)
{
    const float* x      = (const float*)d_in[0];
    const float* w1     = (const float*)d_in[1];
    const float* w2     = (const float*)d_in[2];
    const float* filler = (const float*)d_in[3];
    const float* cl     = (const float*)d_in[4];
    const float* cr     = (const float*)d_in[5];
    const float* role   = (const float*)d_in[6];
    float* out = (float*)d_out;

    char* ws = (char*)d_ws;
    half_t* Ah  = (half_t*)ws;                       // 512*4096*2   = 4 MiB
    half_t* Bh  = (half_t*)(ws + (4u << 20));        // 2048*4096*2  = 16 MiB
    float*  prt = (float*)(ws + (20u << 20));        // 8*512*2048*4 = 32 MiB

    hipLaunchKernelGGL(k_front, dim3(5121), dim3(256), 0, stream,
                       x, w1, w2, cl, cr, Ah, Bh, out);
    hipLaunchKernelGGL(k_gemm,  dim3(N_DIM / BN, M_DIM / BM, SPLITK), dim3(256), 0, stream,
                       Ah, Bh, prt);
    hipLaunchKernelGGL(k_final, dim3(1024), dim3(256), 0, stream, prt, filler, role, out);
}

// Round 5
// 82.224 us; speedup vs baseline: 1.0964x; 1.0589x over previous
//
#include <hip/hip_runtime.h>
#include <hip/hip_bf16.h>
#include <stdint.h>

#define B_DIM 8
#define L_DIM 64
#define F_DIM 64
#define R_DIM 2048
#define M_DIM 512      // B*F
#define K_DIM 4096     // 2*R (concat arg1|arg2 along K)
#define N_DIM 2048     // s

typedef _Float16 half_t;
typedef _Float16 half4 __attribute__((ext_vector_type(4)));
typedef _Float16 half8 __attribute__((ext_vector_type(8)));
typedef float floatx4 __attribute__((ext_vector_type(4)));
typedef float f4 __attribute__((ext_vector_type(4)));

// ---------------- kernel 1 (fused front), 512-thread blocks ----------------
// blocks 0..511      : weighted reduce over L  -> Ah [512][4096] fp16
//                      (one block per (b,f) row; 8KB contiguous read per l)
// blocks 512..2559   : cons_l/cons_r f32 -> fp16 B^T layout [2048][4096]
// block  2560        : row maxes of w1/w2 -> out[1M .. 1M+15]
__global__ __launch_bounds__(512) void k_front(
    const float* __restrict__ x, const float* __restrict__ w1,
    const float* __restrict__ w2, const float* __restrict__ cl,
    const float* __restrict__ cr, half_t* __restrict__ Ah,
    half_t* __restrict__ Bh, float* __restrict__ out)
{
    const int tid = threadIdx.x;
    const int bid = blockIdx.x;

    if (bid < 512) {
        // ---- weighted reduce over L: block owns row (b,f), full r ----
        __shared__ float w1s[L_DIM], w2s[L_DIM];
        const int bf = bid;
        const int b  = bf >> 6;
        const int f  = bf & 63;
        if (tid < L_DIM) {
            w1s[tid] = w1[b * L_DIM + tid];
            w2s[tid] = w2[b * L_DIM + tid];
        }
        __syncthreads();
        const int r0 = tid * 4;                     // 512*4 = 2048 = R
        const f4* xp = (const f4*)(x + ((size_t)(b * 4096 + f)) * 2048 + r0);
        float a1x=0.f,a1y=0.f,a1z=0.f,a1w=0.f;
        float a2x=0.f,a2y=0.f,a2z=0.f,a2w=0.f;
        #pragma unroll 8
        for (int l = 0; l < L_DIM; ++l) {
            f4 v = __builtin_nontemporal_load(xp + (size_t)l * (F_DIM * R_DIM / 4));
            float u1 = w1s[l], u2 = w2s[l];
            a1x += v.x*u1; a1y += v.y*u1; a1z += v.z*u1; a1w += v.w*u1;
            a2x += v.x*u2; a2y += v.y*u2; a2z += v.z*u2; a2w += v.w*u2;
        }
        half4 h1 = { (half_t)a1x, (half_t)a1y, (half_t)a1z, (half_t)a1w };
        half4 h2 = { (half_t)a2x, (half_t)a2y, (half_t)a2z, (half_t)a2w };
        *(half4*)(Ah + (size_t)bf * K_DIM + r0) = h1;
        *(half4*)(Ah + (size_t)bf * K_DIM + R_DIM + r0) = h2;
    } else if (bid < 2560) {
        // ---- cons conversion to fp16 B^T layout ----
        const int i = ((bid - 512) * 512 + tid) * 4;   // 0 .. 4M-4
        const int s = i >> 11;
        const int r = i & 2047;
        f4 vl = __builtin_nontemporal_load((const f4*)(cl + i));
        f4 vr = __builtin_nontemporal_load((const f4*)(cr + i));
        half4 hl = { (half_t)vl.x, (half_t)vl.y, (half_t)vl.z, (half_t)vl.w };
        half4 hr = { (half_t)vr.x, (half_t)vr.y, (half_t)vr.z, (half_t)vr.w };
        *(half4*)(Bh + (size_t)s * K_DIM + r) = hl;
        *(half4*)(Bh + (size_t)s * K_DIM + R_DIM + r) = hr;
    } else {
        // ---- row maxes ----
        if (tid < 16) {
            const float* src = (tid < 8) ? w1 : w2;
            const int b = tid & 7;
            float m = -1.f;
            #pragma unroll 8
            for (int l = 0; l < L_DIM; ++l)
                m = fmaxf(m, src[b * L_DIM + l]);
            out[M_DIM * N_DIM + tid] = m;
        }
    }
}

// ---------------- kernel 2: MFMA GEMM with split-K ----------------
__device__ __forceinline__ void gload16(void* lds, const void* g)
{
    __builtin_amdgcn_global_load_lds(
        (const __attribute__((address_space(1))) void*)g,
        (__attribute__((address_space(3))) void*)lds, 16, 0, 0);
}

#define BM 128
#define BN 128
#define BK 64
#define SPLITK 8
#define KSEG (K_DIM / SPLITK)  // 512
#define NSTEP (KSEG / BK)      // 8

__global__ __launch_bounds__(256) void k_gemm(
    const half_t* __restrict__ Ah, const half_t* __restrict__ Bh,
    float* __restrict__ part)
{
    // LDS tiles [128 rows][64 halfs], XOR-swizzled: logical col-block cb of
    // row lives at physical slot cb ^ (row&7). global_load_lds writes
    // linearly (base + lane*16B), so the swizzle is applied by permuting the
    // per-lane GLOBAL source address (m173 pattern).
    __shared__ half_t sA[2][BM * BK];
    __shared__ half_t sB[2][BN * BK];
    const int tid  = threadIdx.x;
    const int lane = tid & 63;
    const int w    = tid >> 6;           // wave 0..3
    const int wr   = w >> 1, wc = w & 1; // 2x2 wave grid, 64x64 each
    const int m0   = blockIdx.y * BM;
    const int n0   = blockIdx.x * BN;
    const int kz   = blockIdx.z * KSEG;

    const int srow = lane >> 3;                    // dest row within 8-row chunk
    const int scol = ((lane & 7) ^ srow) << 3;     // swizzled source col (halfs)

    const floatx4 fzero = { 0.f, 0.f, 0.f, 0.f };
    floatx4 acc[4][4];
    #pragma unroll
    for (int i = 0; i < 4; ++i)
        #pragma unroll
        for (int j = 0; j < 4; ++j) acc[i][j] = fzero;

    auto stage = [&](int buf, int kt) {
        #pragma unroll
        for (int c = 0; c < 4; ++c) {
            const int rbase = w * 32 + c * 8;      // wave-uniform
            const int row   = rbase + srow;
            gload16(&sA[buf][rbase * BK], Ah + (size_t)(m0 + row) * K_DIM + kt + scol);
            gload16(&sB[buf][rbase * BK], Bh + (size_t)(n0 + row) * K_DIM + kt + scol);
        }
    };

    stage(0, kz);
    __syncthreads();

    const int l15 = lane & 15, l4 = lane >> 4;
    int buf = 0;
    for (int ks = 0; ks < NSTEP; ++ks) {
        if (ks + 1 < NSTEP) stage(buf ^ 1, kz + (ks + 1) * BK);
        #pragma unroll
        for (int ksub = 0; ksub < 2; ++ksub) {
            half8 af[4], bfr[4];
            const int cb = ksub * 4 + l4;          // logical col-block 0..7
            #pragma unroll
            for (int mi = 0; mi < 4; ++mi) {
                const int row = wr * 64 + mi * 16 + l15;
                af[mi] = *(const half8*)&sA[buf][row * BK + ((cb ^ (row & 7)) << 3)];
            }
            #pragma unroll
            for (int ni = 0; ni < 4; ++ni) {
                const int row = wc * 64 + ni * 16 + l15;
                bfr[ni] = *(const half8*)&sB[buf][row * BK + ((cb ^ (row & 7)) << 3)];
            }
            #pragma unroll
            for (int mi = 0; mi < 4; ++mi)
                #pragma unroll
                for (int ni = 0; ni < 4; ++ni)
                    acc[mi][ni] = __builtin_amdgcn_mfma_f32_16x16x32_f16(
                        af[mi], bfr[ni], acc[mi][ni], 0, 0, 0);
        }
        __syncthreads();
        buf ^= 1;
    }

    float* P = part + (size_t)blockIdx.z * ((size_t)M_DIM * N_DIM);
    #pragma unroll
    for (int mi = 0; mi < 4; ++mi) {
        const int rb = m0 + wr * 64 + mi * 16 + l4 * 4;
        #pragma unroll
        for (int ni = 0; ni < 4; ++ni) {
            const int cc = n0 + wc * 64 + ni * 16 + l15;
            #pragma unroll
            for (int r = 0; r < 4; ++r)
                P[(size_t)(rb + r) * N_DIM + cc] = acc[mi][ni][r];
        }
    }
}

// ---------------- kernel 3: reduce split-K partials + root outer product ----------------
__global__ __launch_bounds__(256) void k_final(
    const float* __restrict__ part, const float* __restrict__ filler,
    const float* __restrict__ role, float* __restrict__ out)
{
    const int idx = (blockIdx.x * 256 + threadIdx.x) * 4;  // over 1M outputs
    const int mfi = idx >> 11;          // b*64+f
    const int s   = idx & 2047;
    float4 a = *(const float4*)(part + idx);
    #pragma unroll
    for (int z = 1; z < SPLITK; ++z) {
        float4 p = *(const float4*)(part + (size_t)z * (M_DIM * N_DIM) + idx);
        a.x += p.x; a.y += p.y; a.z += p.z; a.w += p.w;
    }
    const float fl = filler[mfi];
    float4 ro = *(const float4*)(role + s);
    a.x += fl * ro.x; a.y += fl * ro.y; a.z += fl * ro.z; a.w += fl * ro.w;
    *(float4*)(out + idx) = a;
}

extern "C" void kernel_launch(void* const* d_in, const int* in_sizes, int n_in,
                              void* d_out, int out_size, void* d_ws, size_t ws_size,
                              hipStream_t stream)
{
    const float* x      = (const float*)d_in[0];
    const float* w1     = (const float*)d_in[1];
    const float* w2     = (const float*)d_in[2];
    const float* filler = (const float*)d_in[3];
    const float* cl     = (const float*)d_in[4];
    const float* cr     = (const float*)d_in[5];
    const float* role   = (const float*)d_in[6];
    float* out = (float*)d_out;

    char* ws = (char*)d_ws;
    half_t* Ah  = (half_t*)ws;                       // 512*4096*2   = 4 MiB
    half_t* Bh  = (half_t*)(ws + (4u << 20));        // 2048*4096*2  = 16 MiB
    float*  prt = (float*)(ws + (20u << 20));        // 8*512*2048*4 = 32 MiB

    hipLaunchKernelGGL(k_front, dim3(2561), dim3(512), 0, stream,
                       x, w1, w2, cl, cr, Ah, Bh, out);
    hipLaunchKernelGGL(k_gemm,  dim3(N_DIM / BN, M_DIM / BM, SPLITK), dim3(256), 0, stream,
                       Ah, Bh, prt);
    hipLaunchKernelGGL(k_final, dim3(1024), dim3(256), 0, stream, prt, filler, role, out);
}